// Round 10
// baseline (69.856 us; speedup 1.0000x reference)
//
#include <hip/hip_runtime.h>

#define THREADS 256
#define WPP 7                 // puzzles per wave (63 lanes used, lane 63 idle)

typedef float f4 __attribute__((ext_vector_type(4)));
typedef f4 f4a4 __attribute__((aligned(4)));
typedef int i4 __attribute__((ext_vector_type(4)));
typedef i4 i4a4 __attribute__((aligned(4)));
typedef __fp16 h2 __attribute__((ext_vector_type(2)));
typedef unsigned int u32;

static __device__ __forceinline__ h2 shd_h2(h2 v, int d) {
  u32 x = __builtin_bit_cast(u32, v);
  x = __shfl_down(x, d);
  return __builtin_bit_cast(h2, x);
}
// sum of v over the 9 lanes [base, base+8]; result valid at group-base lane
static __device__ __forceinline__ h2 red9(h2 v) {
  h2 t = v + shd_h2(v, 1);
  t = t + shd_h2(t, 2);
  t = t + shd_h2(t, 4);
  return t + shd_h2(v, 8);
}
// sum over 3 lanes [base, base+2]; valid at base
static __device__ __forceinline__ h2 red3(h2 v) {
  return v + shd_h2(v, 1) + shd_h2(v, 2);
}

__global__ __launch_bounds__(THREADS) void sudoku_main(
    const float* __restrict__ logits,
    const int*   __restrict__ targets,
    const int*   __restrict__ puzzles,
    float* __restrict__ partial,       // [5][nblk]
    int B, int nblk)
{
  __shared__ float sred[4][5];

  const int tid  = threadIdx.x;
  const int wv   = tid >> 6, lane = tid & 63;
  const long wpass = (long)blockIdx.x * 4 + wv;   // global wave index
  const int o    = lane % 9;                      // row within puzzle
  const int pzl  = lane / 9;                      // 0..6 (7 -> lane 63 idle)
  const long pzG = wpass * WPP + pzl;
  const bool valid = (lane < 63) && (pzG < (long)B);

  float a_focal=0.f, a_ent=0.f, a_msk=0.f, a_uniq=0.f, a_sq=0.f;

  h2 p45[45];                                     // [col 0..8][pair 0..4], static idx only
  {
    h2 hz; hz[0] = (__fp16)0.f; hz[1] = (__fp16)0.f;
#pragma unroll
    for (int i = 0; i < 45; ++i) p45[i] = hz;
  }

  if (valid) {
    const long cellBase = pzG * 81 + (long)o * 9;
    const float* fb = logits + cellBase * 9;      // 81 floats, this row's logits
    const int*  tb  = targets + cellBase;
    const int*  pb  = puzzles + cellBase;
    i4 tg0 = *(const i4a4*)tb, tg1 = *(const i4a4*)(tb + 4);
    i4 pz0 = *(const i4a4*)pb, pz1 = *(const i4a4*)(pb + 4);
    const int tgs[9] = {tg0[0],tg0[1],tg0[2],tg0[3],tg1[0],tg1[1],tg1[2],tg1[3],tb[8]};
    const int pzs[9] = {pz0[0],pz0[1],pz0[2],pz0[3],pz1[0],pz1[1],pz1[2],pz1[3],pb[8]};

#pragma unroll
    for (int k = 0; k < 9; ++k) {                 // cell k = column k of this row
      f4 va = *(const f4a4*)(fb + 9 * k);
      f4 vb = *(const f4a4*)(fb + 9 * k + 4);
      float l[9] = {va[0],va[1],va[2],va[3],vb[0],vb[1],vb[2],vb[3], fb[9*k+8]};
      int tg = tgs[k] - 1; tg = tg < 0 ? 0 : (tg > 8 ? 8 : tg);

      float t1 = l[0], t2 = -3.0e38f;             // branchless top-2 of logits
#pragma unroll
      for (int i = 1; i < 9; ++i) {
        float hi = fmaxf(t1, l[i]);
        float lo = fminf(t1, l[i]);
        t1 = hi; t2 = fmaxf(t2, lo);
      }
      float e[9], ssum = 0.f, lsum = 0.f, ltg = l[0];
#pragma unroll
      for (int i = 0; i < 9; ++i) {
        float x  = l[i] - t1;
        float ei = __expf(x);
        e[i] = ei; ssum += ei;
        lsum = fmaf(ei, x, lsum);
        if (i > 0) ltg = (tg == i) ? l[i] : ltg;
      }
      float inv_s = __builtin_amdgcn_rcpf(ssum);
      float logs  = __logf(ssum);
      float lpt   = (ltg - t1) - logs;
      float pt    = __expf(lpt);
      float om    = 1.f - pt;
      float focal = om * om * (-lpt);
      float ent   = logs - lsum * inv_s;
      float gap   = (1.f - __expf(t2 - t1)) * inv_s;
      float uq    = fmaxf(0.f, 1.f - gap);
      float mk    = (pzs[k] == 0) ? 1.f : 0.f;
      a_focal += focal * mk;
      a_ent   += ent * mk;
      a_msk   += mk;
      a_uniq  += uq;                              // uniqueness is unmasked
      float pm = inv_s * mk;
      h2 hpm = __builtin_amdgcn_cvt_pkrtz(pm, pm);
      p45[5*k+0] = __builtin_amdgcn_cvt_pkrtz(e[0], e[1]) * hpm;
      p45[5*k+1] = __builtin_amdgcn_cvt_pkrtz(e[2], e[3]) * hpm;
      p45[5*k+2] = __builtin_amdgcn_cvt_pkrtz(e[4], e[5]) * hpm;
      p45[5*k+3] = __builtin_amdgcn_cvt_pkrtz(e[6], e[7]) * hpm;
      p45[5*k+4] = __builtin_amdgcn_cvt_pkrtz(e[8], 0.f)  * hpm;
    }

    // ---- row sums: fully lane-local ----
#pragma unroll
    for (int j = 0; j < 5; ++j) {
      h2 s = p45[j];
#pragma unroll
      for (int c = 1; c < 9; ++c) s = s + p45[5*c+j];
      float x = (float)s[0] - 1.f; a_sq = fmaf(x, x, a_sq);
      if (j < 4) { float y = (float)s[1] - 1.f; a_sq = fmaf(y, y, a_sq); }
    }
  }

  // ---- boxes: per-lane col-triple partials, reduce over 3 rows (shuffles on ALL lanes) ----
  h2 bx[15];
#pragma unroll
  for (int b = 0; b < 3; ++b)
#pragma unroll
    for (int j = 0; j < 5; ++j)
      bx[b*5+j] = p45[(3*b)*5+j] + p45[(3*b+1)*5+j] + p45[(3*b+2)*5+j];
#pragma unroll
  for (int i = 0; i < 15; ++i) bx[i] = red3(bx[i]);
  if (valid && (o == 0 || o == 3 || o == 6)) {    // band-base rows own 3 boxes each
#pragma unroll
    for (int i = 0; i < 15; ++i) {
      float x = (float)bx[i][0] - 1.f; a_sq = fmaf(x, x, a_sq);
      if ((i % 5) < 4) { float y = (float)bx[i][1] - 1.f; a_sq = fmaf(y, y, a_sq); }
    }
  }

  // ---- cols: reduce over the 9 rows of the puzzle (9-lane group), in place ----
#pragma unroll
  for (int i = 0; i < 45; ++i) p45[i] = red9(p45[i]);
  if (valid && o == 0) {                          // group base owns all 9 cols
#pragma unroll
    for (int i = 0; i < 45; ++i) {
      float x = (float)p45[i][0] - 1.f; a_sq = fmaf(x, x, a_sq);
      if ((i % 5) < 4) { float y = (float)p45[i][1] - 1.f; a_sq = fmaf(y, y, a_sq); }
    }
  }

  // ---- wave + block reduction, transposed partial store (no atomics) ----
#pragma unroll
  for (int off = 32; off > 0; off >>= 1) {
    a_focal += __shfl_down(a_focal, off);
    a_ent   += __shfl_down(a_ent,   off);
    a_msk   += __shfl_down(a_msk,   off);
    a_uniq  += __shfl_down(a_uniq,  off);
    a_sq    += __shfl_down(a_sq,    off);
  }
  if (lane == 0) {
    sred[wv][0] = a_focal; sred[wv][1] = a_ent; sred[wv][2] = a_msk;
    sred[wv][3] = a_uniq;  sred[wv][4] = a_sq;
  }
  __syncthreads();
  if (tid < 5) {
    float v = sred[0][tid] + sred[1][tid] + sred[2][tid] + sred[3][tid];
    partial[(size_t)tid * nblk + blockIdx.x] = v;
  }
}

__global__ __launch_bounds__(1024) void sudoku_finalize(
    const float* __restrict__ partial, float* __restrict__ out,
    int nblk, float invBG)
{
  __shared__ float sb[16][5];
  const int tid = threadIdx.x;
  float s[5] = {0.f, 0.f, 0.f, 0.f, 0.f};
  for (int b = tid; b < nblk; b += 1024) {
#pragma unroll
    for (int u = 0; u < 5; ++u) s[u] += partial[(size_t)u * nblk + b];   // coalesced
  }
#pragma unroll
  for (int off = 32; off > 0; off >>= 1)
#pragma unroll
    for (int u = 0; u < 5; ++u) s[u] += __shfl_down(s[u], off);
  const int wv = tid >> 6, lane = tid & 63;
  if (lane == 0) {
#pragma unroll
    for (int u = 0; u < 5; ++u) sb[wv][u] = s[u];
  }
  __syncthreads();
  if (tid == 0) {
    float focal = 0.f, ent = 0.f, msum = 0.f, uniq = 0.f, sq = 0.f;
#pragma unroll
    for (int w = 0; w < 16; ++w) {
      focal += sb[w][0]; ent += sb[w][1]; msum += sb[w][2];
      uniq  += sb[w][3]; sq  += sb[w][4];
    }
    float inv_m = 1.f / (msum + 1e-8f);
    float ce    = focal * inv_m;
    float entl  = 0.1f * ent * inv_m;
    float uql   = 0.1f * uniq * invBG;
    float rcb   = sq * invBG;        // row+col+box means share denominator B*81
    float constraint = (rcb + entl + uql) * 0.2f;
    out[0] = ce + 0.5f * constraint;
  }
}

extern "C" void kernel_launch(void* const* d_in, const int* in_sizes, int n_in,
                              void* d_out, int out_size, void* d_ws, size_t ws_size,
                              hipStream_t stream)
{
  (void)n_in; (void)out_size; (void)ws_size;
  const float* logits  = (const float*)d_in[0];
  const int*   targets = (const int*)d_in[1];
  const int*   puzzles = (const int*)d_in[2];
  float* out = (float*)d_out;
  float* partial = (float*)d_ws;

  const int B = in_sizes[0] / 729;                 // B*9*9*9 logits
  const long npass = ((long)B + WPP - 1) / WPP;    // waves of work
  const int  nblk  = (int)((npass + 3) / 4);       // 4 waves per block

  sudoku_main<<<nblk, THREADS, 0, stream>>>(logits, targets, puzzles, partial, B, nblk);

  const float invBG = 1.f / ((float)B * 81.f);
  sudoku_finalize<<<1, 1024, 0, stream>>>(partial, out, nblk, invBG);
}